// Round 1
// baseline (4480.721 us; speedup 1.0000x reference)
//
#include <hip/hip_runtime.h>

constexpr int BLK = 256;

static inline int nblk(long long total) { return (int)((total + BLK - 1) / BLK); }

// ---------- degree / norm ----------
__global__ void k_init_deg(float* __restrict__ deg, int N) {
    int i = blockIdx.x * blockDim.x + threadIdx.x;
    if (i < N) deg[i] = 1.0f;  // self-loop
}

__global__ void k_deg(const int* __restrict__ dst, float* __restrict__ deg, int E) {
    int i = blockIdx.x * blockDim.x + threadIdx.x;
    if (i < E) atomicAdd(&deg[dst[i]], 1.0f);
}

__global__ void k_rsqrt(float* __restrict__ d, int N) {
    int i = blockIdx.x * blockDim.x + threadIdx.x;
    if (i < N) d[i] = rsqrtf(d[i]);
}

// ---------- self-loop contribution (also initializes agg buffer) ----------
template<int D>
__global__ void k_self_init(const float* __restrict__ feat, const float* __restrict__ dinv,
                            float* __restrict__ agg, int N) {
    long long gid = (long long)blockIdx.x * blockDim.x + threadIdx.x;
    if (gid >= (long long)N * D) return;
    int i = (int)(gid / D);
    float w = dinv[i]; w *= w;
    agg[gid] = w * feat[gid];
}

// ---------- edge scatter: agg[dst] += dinv[src]*dinv[dst] * feat[src] ----------
template<int D, int VEC>   // TPE = D/VEC threads per edge
__global__ void k_edge(const int* __restrict__ src, const int* __restrict__ dst,
                       const float* __restrict__ dinv, const float* __restrict__ feat,
                       float* __restrict__ agg, int E) {
    constexpr int TPE = D / VEC;
    long long gid = (long long)blockIdx.x * blockDim.x + threadIdx.x;
    if (gid >= (long long)E * TPE) return;
    int e  = (int)(gid / TPE);
    int d0 = (int)(gid % TPE) * VEC;
    int s = src[e], t = dst[e];
    float w = dinv[s] * dinv[t];
    const float* fp = feat + (long long)s * D + d0;
    float*       ap = agg  + (long long)t * D + d0;
    if constexpr (VEC == 4) {
        float4 v = *reinterpret_cast<const float4*>(fp);
        atomicAdd(ap + 0, w * v.x);
        atomicAdd(ap + 1, w * v.y);
        atomicAdd(ap + 2, w * v.z);
        atomicAdd(ap + 3, w * v.w);
    } else {
        #pragma unroll
        for (int k = 0; k < VEC; ++k) atomicAdd(ap + k, w * fp[k]);
    }
}

// ---------- dense transform: out = act(in @ W + b) ----------
template<int DIN, int DOUT, bool BIAS, bool RELU>
__global__ void k_transform(const float* __restrict__ in, const float* __restrict__ W,
                            const float* __restrict__ b, float* __restrict__ out, int N) {
    __shared__ float sW[DIN * DOUT];
    __shared__ float sb[DOUT];
    for (int k = threadIdx.x; k < DIN * DOUT; k += blockDim.x) sW[k] = W[k];
    if (BIAS) for (int k = threadIdx.x; k < DOUT; k += blockDim.x) sb[k] = b[k];
    __syncthreads();
    long long gid = (long long)blockIdx.x * blockDim.x + threadIdx.x;
    if (gid >= (long long)N * DOUT) return;
    int i = (int)(gid / DOUT), j = (int)(gid % DOUT);
    const float* row = in + (long long)i * DIN;
    float acc = BIAS ? sb[j] : 0.0f;
    #pragma unroll
    for (int d = 0; d < DIN; ++d) acc = fmaf(row[d], sW[d * DOUT + j], acc);
    out[gid] = RELU ? fmaxf(acc, 0.0f) : acc;
}

// ---------- final: out = log_softmax(out + b), 5 classes, in-place ----------
__global__ void k_logsoftmax5(float* __restrict__ io, const float* __restrict__ b, int N) {
    int i = blockIdx.x * blockDim.x + threadIdx.x;
    if (i >= N) return;
    float v[5];
    #pragma unroll
    for (int j = 0; j < 5; ++j) v[j] = io[(long long)i * 5 + j] + b[j];
    float m = v[0];
    #pragma unroll
    for (int j = 1; j < 5; ++j) m = fmaxf(m, v[j]);
    float s = 0.0f;
    #pragma unroll
    for (int j = 0; j < 5; ++j) s += expf(v[j] - m);
    float ls = m + logf(s);
    #pragma unroll
    for (int j = 0; j < 5; ++j) io[(long long)i * 5 + j] = v[j] - ls;
}

extern "C" void kernel_launch(void* const* d_in, const int* in_sizes, int n_in,
                              void* d_out, int out_size, void* d_ws, size_t ws_size,
                              hipStream_t stream) {
    const float* x  = (const float*)d_in[0];
    const int*   ei = (const int*)d_in[1];   // [2, E] int32 (JAX default x64-off)
    const float* W1 = (const float*)d_in[2];
    const float* b1 = (const float*)d_in[3];
    const float* W2 = (const float*)d_in[4];
    const float* b2 = (const float*)d_in[5];
    const float* W3 = (const float*)d_in[6];
    const float* b3 = (const float*)d_in[7];
    const float* W4 = (const float*)d_in[8];
    const float* b4 = (const float*)d_in[9];

    const int N = in_sizes[0];        // 100000
    const int E = in_sizes[1] / 2;    // 3200000
    float* out = (float*)d_out;

    const int* src = ei;
    const int* dst = ei + E;

    // workspace layout
    char* p = (char*)d_ws;
    float* dinv = (float*)p; p += sizeof(float) * (size_t)N;
    float* bufA = (float*)p; p += sizeof(float) * (size_t)N * 64;
    float* bufB = (float*)p; p += sizeof(float) * (size_t)N * 64;
    (void)ws_size; (void)n_in; (void)out_size;

    // ---- degree -> dinv (deg >= 1 due to self-loops) ----
    k_init_deg<<<nblk(N), BLK, 0, stream>>>(dinv, N);
    k_deg<<<nblk(E), BLK, 0, stream>>>(dst, dinv, E);
    k_rsqrt<<<nblk(N), BLK, 0, stream>>>(dinv, N);

    // ---- Layer 1: aggregate x (1-dim) then transform 1->16 (ReLU) ----
    k_self_init<1><<<nblk(N), BLK, 0, stream>>>(x, dinv, bufA, N);
    k_edge<1, 1><<<nblk(E), BLK, 0, stream>>>(src, dst, dinv, x, bufA, E);
    k_transform<1, 16, true, true><<<nblk((long long)N * 16), BLK, 0, stream>>>(bufA, W1, b1, bufB, N);

    // ---- Layer 2: aggregate h1 (16-dim) then transform 16->64 (ReLU) ----
    k_self_init<16><<<nblk((long long)N * 16), BLK, 0, stream>>>(bufB, dinv, bufA, N);
    k_edge<16, 4><<<nblk((long long)E * 4), BLK, 0, stream>>>(src, dst, dinv, bufB, bufA, E);
    k_transform<16, 64, true, true><<<nblk((long long)N * 64), BLK, 0, stream>>>(bufA, W2, b2, bufB, N);

    // ---- Layer 3: aggregate h2 (64-dim) then transform 64->64 (ReLU) ----
    k_self_init<64><<<nblk((long long)N * 64), BLK, 0, stream>>>(bufB, dinv, bufA, N);
    k_edge<64, 4><<<nblk((long long)E * 16), BLK, 0, stream>>>(src, dst, dinv, bufB, bufA, E);
    k_transform<64, 64, true, true><<<nblk((long long)N * 64), BLK, 0, stream>>>(bufA, W3, b3, bufB, N);

    // ---- Layer 4: transform 64->5 (no bias), aggregate 5-dim into d_out, log_softmax ----
    k_transform<64, 5, false, false><<<nblk((long long)N * 5), BLK, 0, stream>>>(bufB, W4, nullptr, bufA, N);
    k_self_init<5><<<nblk((long long)N * 5), BLK, 0, stream>>>(bufA, dinv, out, N);
    k_edge<5, 5><<<nblk(E), BLK, 0, stream>>>(src, dst, dinv, bufA, out, E);
    k_logsoftmax5<<<nblk(N), BLK, 0, stream>>>(out, b4, N);
}

// Round 2
// 775.970 us; speedup vs baseline: 5.7743x; 5.7743x over previous
//
#include <hip/hip_runtime.h>

constexpr int BLK = 256;
static inline int nblk(long long total, int blk = BLK) { return (int)((total + blk - 1) / blk); }

// ---------- utility ----------
__global__ void k_zero_i32(int* __restrict__ p, int n) {
    int i = blockIdx.x * blockDim.x + threadIdx.x;
    if (i < n) p[i] = 0;
}

// ---------- CSR build ----------
__global__ void k_hist(const int* __restrict__ dst, int* __restrict__ cnt, int E) {
    int e = blockIdx.x * blockDim.x + threadIdx.x;
    if (e < E) atomicAdd(&cnt[dst[e]], 1);
}

// block-level exclusive scan (Hillis-Steele in LDS), emits block sums
__global__ void k_scan_block(int* __restrict__ data, int* __restrict__ sums, int n) {
    __shared__ int s[256];
    int i = blockIdx.x * 256 + threadIdx.x;
    int v = (i < n) ? data[i] : 0;
    s[threadIdx.x] = v;
    __syncthreads();
    for (int off = 1; off < 256; off <<= 1) {
        int t = (threadIdx.x >= off) ? s[threadIdx.x - off] : 0;
        __syncthreads();
        s[threadIdx.x] += t;
        __syncthreads();
    }
    if (i < n) data[i] = s[threadIdx.x] - v;          // exclusive
    if (threadIdx.x == 255) sums[blockIdx.x] = s[255]; // block total
}

// single-block exclusive scan of the block sums (n <= 512)
__global__ void k_scan_sums(int* __restrict__ sums, int n) {
    __shared__ int s[512];
    int i = threadIdx.x;
    int v = (i < n) ? sums[i] : 0;
    s[i] = v;
    __syncthreads();
    for (int off = 1; off < 512; off <<= 1) {
        int t = (i >= off) ? s[i - off] : 0;
        __syncthreads();
        s[i] += t;
        __syncthreads();
    }
    if (i < n) sums[i] = s[i] - v; // exclusive
}

__global__ void k_scan_add(int* __restrict__ data, const int* __restrict__ sums, int n) {
    int i = blockIdx.x * 256 + threadIdx.x;
    if (i < n) data[i] += sums[blockIdx.x];
}

__global__ void k_dinv(const int* __restrict__ rowptr, float* __restrict__ dinv, int N) {
    int i = blockIdx.x * blockDim.x + threadIdx.x;
    if (i < N) dinv[i] = rsqrtf((float)(rowptr[i + 1] - rowptr[i] + 1)); // +1 self-loop
}

__global__ void k_fill(const int* __restrict__ src, const int* __restrict__ dst,
                       const int* __restrict__ rowptr, int* __restrict__ cursor,
                       int* __restrict__ col, int E) {
    int e = blockIdx.x * blockDim.x + threadIdx.x;
    if (e < E) {
        int d = dst[e];
        int pos = atomicAdd(&cursor[d], 1);
        col[rowptr[d] + pos] = src[e];
    }
}

// ---------- gather aggregation: out[i] = dinv[i]*(dinv[i]*feat[i] + sum_s dinv[s]*feat[s]) ----------
template<int D, int BLKA>
__global__ void k_agg(const int* __restrict__ col, const int* __restrict__ rowptr,
                      const float* __restrict__ dinv, const float* __restrict__ feat,
                      float* __restrict__ out, int N) {
    constexpr int NPB = BLKA / D;
    int g = threadIdx.x / D, d = threadIdx.x % D;
    int i = blockIdx.x * NPB + g;
    if (i >= N) return;
    int beg = rowptr[i], end = rowptr[i + 1];
    float di = dinv[i];
    float acc = di * feat[(size_t)i * D + d]; // self-loop term (one dinv factor applied at end)
    int e = beg;
    for (; e + 1 < end; e += 2) { // 2-way unroll for load ILP
        int s0 = col[e], s1 = col[e + 1];
        float w0 = dinv[s0], w1 = dinv[s1];
        float f0 = feat[(size_t)s0 * D + d], f1 = feat[(size_t)s1 * D + d];
        acc = fmaf(w0, f0, acc);
        acc = fmaf(w1, f1, acc);
    }
    if (e < end) {
        int s = col[e];
        acc = fmaf(dinv[s], feat[(size_t)s * D + d], acc);
    }
    out[(size_t)i * D + d] = di * acc;
}

// ---------- dense transform: out = act(in @ W + b) ----------
template<int DIN, int DOUT, bool BIAS, bool RELU>
__global__ void k_transform(const float* __restrict__ in, const float* __restrict__ W,
                            const float* __restrict__ b, float* __restrict__ out, int N) {
    __shared__ float sW[DIN * DOUT];
    __shared__ float sb[DOUT];
    for (int k = threadIdx.x; k < DIN * DOUT; k += blockDim.x) sW[k] = W[k];
    if (BIAS) for (int k = threadIdx.x; k < DOUT; k += blockDim.x) sb[k] = b[k];
    __syncthreads();
    long long gid = (long long)blockIdx.x * blockDim.x + threadIdx.x;
    if (gid >= (long long)N * DOUT) return;
    int i = (int)(gid / DOUT), j = (int)(gid % DOUT);
    const float* row = in + (long long)i * DIN;
    float acc = BIAS ? sb[j] : 0.0f;
    #pragma unroll
    for (int d = 0; d < DIN; ++d) acc = fmaf(row[d], sW[d * DOUT + j], acc);
    out[gid] = RELU ? fmaxf(acc, 0.0f) : acc;
}

// ---------- final: out = log_softmax(out + b), 5 classes, in-place ----------
__global__ void k_logsoftmax5(float* __restrict__ io, const float* __restrict__ b, int N) {
    int i = blockIdx.x * blockDim.x + threadIdx.x;
    if (i >= N) return;
    float v[5];
    #pragma unroll
    for (int j = 0; j < 5; ++j) v[j] = io[(long long)i * 5 + j] + b[j];
    float m = v[0];
    #pragma unroll
    for (int j = 1; j < 5; ++j) m = fmaxf(m, v[j]);
    float s = 0.0f;
    #pragma unroll
    for (int j = 0; j < 5; ++j) s += expf(v[j] - m);
    float ls = m + logf(s);
    #pragma unroll
    for (int j = 0; j < 5; ++j) io[(long long)i * 5 + j] = v[j] - ls;
}

extern "C" void kernel_launch(void* const* d_in, const int* in_sizes, int n_in,
                              void* d_out, int out_size, void* d_ws, size_t ws_size,
                              hipStream_t stream) {
    const float* x  = (const float*)d_in[0];
    const int*   ei = (const int*)d_in[1];   // [2, E] int32
    const float* W1 = (const float*)d_in[2];
    const float* b1 = (const float*)d_in[3];
    const float* W2 = (const float*)d_in[4];
    const float* b2 = (const float*)d_in[5];
    const float* W3 = (const float*)d_in[6];
    const float* b3 = (const float*)d_in[7];
    const float* W4 = (const float*)d_in[8];
    const float* b4 = (const float*)d_in[9];

    const int N = in_sizes[0];        // 100000
    const int E = in_sizes[1] / 2;    // 3200000
    float* out = (float*)d_out;
    const int* src = ei;
    const int* dst = ei + E;
    (void)n_in; (void)out_size; (void)ws_size;

    // ---- workspace layout (256B aligned chunks) ----
    auto align_up = [](size_t v) { return (v + 255) & ~(size_t)255; };
    char* p = (char*)d_ws;
    int*   rowptr = (int*)p;   p += align_up(sizeof(int) * (size_t)(N + 1));
    int*   cursor = (int*)p;   p += align_up(sizeof(int) * (size_t)N);
    int*   sums   = (int*)p;   p += align_up(sizeof(int) * 512);
    float* dinv   = (float*)p; p += align_up(sizeof(float) * (size_t)N);
    int*   col    = (int*)p;   p += align_up(sizeof(int) * (size_t)E);
    float* bufA   = (float*)p; p += align_up(sizeof(float) * (size_t)N * 64);
    float* bufB   = (float*)p; p += align_up(sizeof(float) * (size_t)N * 64);

    const int nScan = N + 1;                 // include trailing 0 so rowptr[N] = E after scan
    const int nScanBlk = nblk(nScan);

    // ---- CSR build ----
    k_zero_i32<<<nblk(nScan), BLK, 0, stream>>>(rowptr, nScan);
    k_zero_i32<<<nblk(N), BLK, 0, stream>>>(cursor, N);
    k_hist<<<nblk(E), BLK, 0, stream>>>(dst, rowptr, E);
    k_scan_block<<<nScanBlk, 256, 0, stream>>>(rowptr, sums, nScan);
    k_scan_sums<<<1, 512, 0, stream>>>(sums, nScanBlk);
    k_scan_add<<<nScanBlk, 256, 0, stream>>>(rowptr, sums, nScan);
    k_dinv<<<nblk(N), BLK, 0, stream>>>(rowptr, dinv, N);
    k_fill<<<nblk(E), BLK, 0, stream>>>(src, dst, rowptr, cursor, col, E);

    // ---- Layer 1: aggregate x (D=1) then 1->16 (ReLU) ----
    k_agg<1, 256><<<nblk(N, 256), 256, 0, stream>>>(col, rowptr, dinv, x, bufA, N);
    k_transform<1, 16, true, true><<<nblk((long long)N * 16), BLK, 0, stream>>>(bufA, W1, b1, bufB, N);

    // ---- Layer 2: aggregate (D=16) then 16->64 (ReLU) ----
    k_agg<16, 256><<<nblk(N, 16), 256, 0, stream>>>(col, rowptr, dinv, bufB, bufA, N);
    k_transform<16, 64, true, true><<<nblk((long long)N * 64), BLK, 0, stream>>>(bufA, W2, b2, bufB, N);

    // ---- Layer 3: aggregate (D=64) then 64->64 (ReLU) ----
    k_agg<64, 256><<<nblk(N, 4), 256, 0, stream>>>(col, rowptr, dinv, bufB, bufA, N);
    k_transform<64, 64, true, true><<<nblk((long long)N * 64), BLK, 0, stream>>>(bufA, W3, b3, bufB, N);

    // ---- Layer 4: 64->5 (no bias) then aggregate (D=5) into out, log_softmax ----
    k_transform<64, 5, false, false><<<nblk((long long)N * 5), BLK, 0, stream>>>(bufB, W4, nullptr, bufA, N);
    k_agg<5, 320><<<nblk(N, 64), 320, 0, stream>>>(col, rowptr, dinv, bufA, out, N);
    k_logsoftmax5<<<nblk(N), BLK, 0, stream>>>(out, b4, N);
}